// Round 1
// baseline (408.756 us; speedup 1.0000x reference)
//
#include <hip/hip_runtime.h>

typedef unsigned short u16;
typedef unsigned int u32;

typedef __bf16 bf16x8 __attribute__((ext_vector_type(8)));
typedef float f32x4 __attribute__((ext_vector_type(4)));
typedef u32 u32x2 __attribute__((ext_vector_type(2)));

#define M_DIM 8192
#define F_DIM 32

__device__ __forceinline__ u16 f2bf(float f) {
  u32 u = __builtin_bit_cast(u32, f);
  u += 0x7FFFu + ((u >> 16) & 1u);   // round-to-nearest-even
  return (u16)(u >> 16);
}
__device__ __forceinline__ float bf2f(u16 h) {
  u32 u = ((u32)h) << 16;
  return __builtin_bit_cast(float, u);
}

union Frag {
  bf16x8 f;
  u16 s[8];
  u32x2 h2[2];
};

// x [8192][32] f32 -> zT0 [32][8192] bf16
__global__ __launch_bounds__(256) void transpose_x_kernel(
    const float* __restrict__ x, u16* __restrict__ zT) {
  int m = blockIdx.x * 256 + threadIdx.x;
  const float* xr = x + (size_t)m * F_DIM;
#pragma unroll
  for (int c = 0; c < F_DIM; c++) zT[(size_t)c * M_DIM + m] = f2bf(xr[c]);
}

// One propagation pass: zout^T = bf16( L @ zin ), zT layouts [32][8192].
// Block: 4 waves, all on the same 16 output rows, K split 4x2048.
// A-frag: lane holds L[row0+(l&15)][k + 4*(l>>4) + {0..3}] and +16.
// B-frag: lane holds zT[(l&15)+16*nt][k + 4*(l>>4) + {0..3}] and +16.
// Identical k-mapping for A and B => layout-permutation-safe.
template <bool USEB16, bool WRITEB16>
__global__ __launch_bounds__(256) void pass_kernel(
    const float* __restrict__ Lf, const u16* __restrict__ Lb,
    u16* __restrict__ Lbout, const u16* __restrict__ zin,
    u16* __restrict__ zout) {
  const int tid = threadIdx.x;
  const int wave = tid >> 6;
  const int lane = tid & 63;
  const int l15 = lane & 15;
  const int l4 = lane >> 4;
  const int row0 = blockIdx.x << 4;
  const int row = row0 + l15;
  const int kbase = wave * (M_DIM / 4) + l4 * 4;

  f32x4 acc0 = {0.f, 0.f, 0.f, 0.f};
  f32x4 acc1 = {0.f, 0.f, 0.f, 0.f};

  const u16* bp0 = zin + l15 * M_DIM + kbase;
  const u16* bp1 = bp0 + 16 * M_DIM;

  if constexpr (USEB16) {
    const u16* ap = Lb + (size_t)row * M_DIM + kbase;
#pragma unroll 4
    for (int kk = 0; kk < M_DIM / 4; kk += 32) {
      Frag fa, fb0, fb1;
      fa.h2[0] = *(const u32x2*)(ap + kk);
      fa.h2[1] = *(const u32x2*)(ap + kk + 16);
      fb0.h2[0] = *(const u32x2*)(bp0 + kk);
      fb0.h2[1] = *(const u32x2*)(bp0 + kk + 16);
      fb1.h2[0] = *(const u32x2*)(bp1 + kk);
      fb1.h2[1] = *(const u32x2*)(bp1 + kk + 16);
      acc0 = __builtin_amdgcn_mfma_f32_16x16x32_bf16(fa.f, fb0.f, acc0, 0, 0, 0);
      acc1 = __builtin_amdgcn_mfma_f32_16x16x32_bf16(fa.f, fb1.f, acc1, 0, 0, 0);
    }
  } else {
    const float* ap = Lf + (size_t)row * M_DIM + kbase;
    u16* op = WRITEB16 ? (Lbout + (size_t)row * M_DIM + kbase) : (u16*)0;
#pragma unroll 2
    for (int kk = 0; kk < M_DIM / 4; kk += 32) {
      float4 a0 = *(const float4*)(ap + kk);
      float4 a1 = *(const float4*)(ap + kk + 16);
      Frag fa, fb0, fb1;
      fa.s[0] = f2bf(a0.x); fa.s[1] = f2bf(a0.y);
      fa.s[2] = f2bf(a0.z); fa.s[3] = f2bf(a0.w);
      fa.s[4] = f2bf(a1.x); fa.s[5] = f2bf(a1.y);
      fa.s[6] = f2bf(a1.z); fa.s[7] = f2bf(a1.w);
      if constexpr (WRITEB16) {
        *(u32x2*)(op + kk) = fa.h2[0];
        *(u32x2*)(op + kk + 16) = fa.h2[1];
      }
      fb0.h2[0] = *(const u32x2*)(bp0 + kk);
      fb0.h2[1] = *(const u32x2*)(bp0 + kk + 16);
      fb1.h2[0] = *(const u32x2*)(bp1 + kk);
      fb1.h2[1] = *(const u32x2*)(bp1 + kk + 16);
      acc0 = __builtin_amdgcn_mfma_f32_16x16x32_bf16(fa.f, fb0.f, acc0, 0, 0, 0);
      acc1 = __builtin_amdgcn_mfma_f32_16x16x32_bf16(fa.f, fb1.f, acc1, 0, 0, 0);
    }
  }

  // Cross-wave K reduction. C/D layout: C[4*(l>>4)+r][(l&15)+16*nt]
  __shared__ float red[4][16][33];
#pragma unroll
  for (int r = 0; r < 4; r++) {
    red[wave][l4 * 4 + r][l15] = acc0[r];
    red[wave][l4 * 4 + r][l15 + 16] = acc1[r];
  }
  __syncthreads();
  const int orow = tid & 15;
  const int ocol = tid >> 4;  // 0..15
  float v0 = red[0][orow][ocol] + red[1][orow][ocol] +
             red[2][orow][ocol] + red[3][orow][ocol];
  float v1 = red[0][orow][ocol + 16] + red[1][orow][ocol + 16] +
             red[2][orow][ocol + 16] + red[3][orow][ocol + 16];
  zout[(size_t)ocol * M_DIM + row0 + orow] = f2bf(v0);
  zout[(size_t)(ocol + 16) * M_DIM + row0 + orow] = f2bf(v1);
}

// y[m][j] = x[m]·W0[:,j] + sum_k zTk[:,m]·Wk[:,j]
__global__ __launch_bounds__(256) void finalize_kernel(
    const float* __restrict__ x, const float* __restrict__ W,
    const u16* __restrict__ z1, const u16* __restrict__ z2,
    const u16* __restrict__ z3, const u16* __restrict__ z4,
    float* __restrict__ y) {
  __shared__ float Ws[5 * 32 * 32];
  for (int i = threadIdx.x; i < 5 * 32 * 32; i += 256) Ws[i] = W[i];
  __syncthreads();
  int g = blockIdx.x * 256 + threadIdx.x;
  int m = g >> 2;
  int j0 = (g & 3) * 8;
  float acc[8];
#pragma unroll
  for (int jj = 0; jj < 8; jj++) acc[jj] = 0.f;
  const float* xr = x + (size_t)m * 32;
#pragma unroll
  for (int c = 0; c < 32; c++) {
    float xv = xr[c];
    const float* w = Ws + c * 32 + j0;
#pragma unroll
    for (int jj = 0; jj < 8; jj++) acc[jj] += xv * w[jj];
  }
  const u16* zs[4] = {z1, z2, z3, z4};
#pragma unroll
  for (int k = 0; k < 4; k++) {
    const u16* z = zs[k] + m;
    const float* wk = Ws + (k + 1) * 1024 + j0;
#pragma unroll
    for (int c = 0; c < 32; c++) {
      float zv = bf2f(z[(size_t)c * M_DIM]);
#pragma unroll
      for (int jj = 0; jj < 8; jj++) acc[jj] += zv * wk[c * 32 + jj];
    }
  }
  float* yo = y + (size_t)m * 32 + j0;
#pragma unroll
  for (int jj = 0; jj < 8; jj++) yo[jj] = acc[jj];
}

extern "C" void kernel_launch(void* const* d_in, const int* in_sizes, int n_in,
                              void* d_out, int out_size, void* d_ws,
                              size_t ws_size, hipStream_t stream) {
  const float* x = (const float*)d_in[0];
  const float* L = (const float*)d_in[1];
  const float* W = (const float*)d_in[2];
  float* y = (float*)d_out;
  char* ws = (char*)d_ws;

  const size_t ZT_BYTES = (size_t)F_DIM * M_DIM * sizeof(u16);  // 512 KB
  u16* zT[5];
  for (int i = 0; i < 5; i++) zT[i] = (u16*)(ws + (size_t)i * ZT_BYTES);
  u16* Lb = (u16*)(ws + 5 * ZT_BYTES);
  const size_t LB_BYTES = (size_t)M_DIM * M_DIM * sizeof(u16);  // 134 MB
  const bool big = ws_size >= 5 * ZT_BYTES + LB_BYTES;

  transpose_x_kernel<<<M_DIM / 256, 256, 0, stream>>>(x, zT[0]);

  if (big) {
    pass_kernel<false, true><<<M_DIM / 16, 256, 0, stream>>>(
        L, (const u16*)0, Lb, zT[0], zT[1]);
    pass_kernel<true, false><<<M_DIM / 16, 256, 0, stream>>>(
        (const float*)0, Lb, (u16*)0, zT[1], zT[2]);
    pass_kernel<true, false><<<M_DIM / 16, 256, 0, stream>>>(
        (const float*)0, Lb, (u16*)0, zT[2], zT[3]);
    pass_kernel<true, false><<<M_DIM / 16, 256, 0, stream>>>(
        (const float*)0, Lb, (u16*)0, zT[3], zT[4]);
  } else {
    for (int k = 0; k < 4; k++) {
      pass_kernel<false, false><<<M_DIM / 16, 256, 0, stream>>>(
          L, (const u16*)0, (u16*)0, zT[k], zT[k + 1]);
    }
  }

  finalize_kernel<<<M_DIM * 4 / 256, 256, 0, stream>>>(
      x, W, zT[1], zT[2], zT[3], zT[4], y);
}

// Round 2
// 318.280 us; speedup vs baseline: 1.2843x; 1.2843x over previous
//
#include <hip/hip_runtime.h>

typedef unsigned short u16;
typedef unsigned int u32;
typedef __bf16 bf16x8 __attribute__((ext_vector_type(8)));
typedef float f32x4 __attribute__((ext_vector_type(4)));
typedef u32 u32x4 __attribute__((ext_vector_type(4)));

#define M_DIM 8192
#define S_SPLIT 8
#define CHUNK (M_DIM / S_SPLIT) /* 1024 */
#define BM 64

__device__ __forceinline__ u16 f2bf(float f) {
  u32 u = __builtin_bit_cast(u32, f);
  u += 0x7FFFu + ((u >> 16) & 1u); // RNE
  return (u16)(u >> 16);
}

union Frag {
  bf16x8 f;
  u16 s[8];
  u32x4 q;
};

// ---- head: y_acc = x @ W0 ; zT0 = bf16(x)^T --------------------------------
__global__ __launch_bounds__(256) void head_kernel(
    const float* __restrict__ x, const float* __restrict__ W0,
    float* __restrict__ y_out, u16* __restrict__ zT0) {
  __shared__ float Ws[1024];
  for (int i = threadIdx.x; i < 1024; i += 256) Ws[i] = W0[i];
  __syncthreads();
  int m = blockIdx.x * 256 + threadIdx.x;
  const float4* xr = (const float4*)(x + (size_t)m * 32);
  float z[32];
#pragma unroll
  for (int i = 0; i < 8; i++) {
    float4 v = xr[i];
    z[4 * i] = v.x; z[4 * i + 1] = v.y; z[4 * i + 2] = v.z; z[4 * i + 3] = v.w;
  }
  float acc[32];
#pragma unroll
  for (int j = 0; j < 32; j++) acc[j] = 0.f;
#pragma unroll
  for (int c = 0; c < 32; c++) {
#pragma unroll
    for (int j = 0; j < 32; j++) acc[j] += z[c] * Ws[c * 32 + j];
  }
  float4* yo = (float4*)(y_out + (size_t)m * 32);
#pragma unroll
  for (int i = 0; i < 8; i++) {
    float4 v; v.x = acc[4 * i]; v.y = acc[4 * i + 1];
    v.z = acc[4 * i + 2]; v.w = acc[4 * i + 3];
    yo[i] = v;
  }
#pragma unroll
  for (int c = 0; c < 32; c++) zT0[(size_t)c * M_DIM + m] = f2bf(z[c]);
}

// ---- pass1: z_part = (L @ z0) partials; emits Lbt (bf16, MFMA-frag-tiled) --
// Lbt tile (rt,kt): rows 16*rt..+15, k 32*kt..+31; 1024 B; lane l owns 16 B:
// row = rt*16 + (l&15), k = kt*32 + 8*(l>>4) + j (j=0..7).
__global__ __launch_bounds__(256) void pass1_kernel(
    const float* __restrict__ L, const u16* __restrict__ zin,
    u16* __restrict__ Lbt, float* __restrict__ z_part) {
  __shared__ float lds_a[2][BM * 64]; // 2 x 16 KB, row = 64 f32
  const int t = threadIdx.x;
  const int lane = t & 63;
  const int w = t >> 6;
  const int l15 = lane & 15;
  const int l4 = lane >> 4;
  const int r0 = blockIdx.x * BM;
  const int s = blockIdx.y;
  const int kbase = s * CHUNK;

  f32x4 acc0 = {0.f, 0.f, 0.f, 0.f};
  f32x4 acc1 = {0.f, 0.f, 0.f, 0.f};

  const int lrow_i = 16 * w + l15;
  const int swz = (l15 & 7) << 4;
  const int rt = (r0 >> 4) + w;
  const u16* b0p = zin + (size_t)l15 * M_DIM + kbase + 8 * l4;
  const u16* b1p = b0p + (size_t)16 * M_DIM;

  const int NST = CHUNK / 64; // 16

  auto stage = [&](int st, int buf) {
    const float* Lb0 = L + (size_t)r0 * M_DIM + kbase + st * 64;
#pragma unroll
    for (int it = 0; it < 4; it++) {
      int o4 = (it * 256 + t) * 4;      // f32 idx, lane*16B within wave chunk
      int row = o4 >> 6;                // 64 f32 per LDS row
      int colb = (o4 & 63) << 2;        // byte in row
      int scolb = colb ^ ((row & 7) << 4); // pre-swizzled GLOBAL source
      const float* src = Lb0 + (size_t)row * M_DIM + (scolb >> 2);
      __builtin_amdgcn_global_load_lds(
          (const __attribute__((address_space(1))) u32*)src,
          (__attribute__((address_space(3))) u32*)&lds_a[buf][o4], 16, 0, 0);
    }
  };

  stage(0, 0);
  __syncthreads();
  int cur = 0;
  for (int st = 0; st < NST; st++) {
    if (st + 1 < NST) stage(st + 1, cur ^ 1);
    const char* lrow = (const char*)&lds_a[cur][lrow_i * 64];
#pragma unroll
    for (int ks = 0; ks < 2; ks++) {
      int b0 = ks * 128 + 32 * l4;
      float4 alo = *(const float4*)(lrow + (b0 ^ swz));
      float4 ahi = *(const float4*)(lrow + ((b0 + 16) ^ swz));
      Frag fa;
      fa.s[0] = f2bf(alo.x); fa.s[1] = f2bf(alo.y);
      fa.s[2] = f2bf(alo.z); fa.s[3] = f2bf(alo.w);
      fa.s[4] = f2bf(ahi.x); fa.s[5] = f2bf(ahi.y);
      fa.s[6] = f2bf(ahi.z); fa.s[7] = f2bf(ahi.w);
      int ktile = (kbase >> 5) + st * 2 + ks;
      *(u32x4*)(Lbt + ((size_t)rt * 256 + ktile) * 512 + lane * 8) = fa.q;
      int koff = st * 64 + ks * 32;
      Frag fb0, fb1;
      fb0.q = *(const u32x4*)(b0p + koff);
      fb1.q = *(const u32x4*)(b1p + koff);
      acc0 = __builtin_amdgcn_mfma_f32_16x16x32_bf16(fa.f, fb0.f, acc0, 0, 0, 0);
      acc1 = __builtin_amdgcn_mfma_f32_16x16x32_bf16(fa.f, fb1.f, acc1, 0, 0, 0);
    }
    __syncthreads();
    cur ^= 1;
  }

  float* zpr = z_part + (size_t)s * (M_DIM * 32) +
               (size_t)(r0 + 16 * w + 4 * l4) * 32 + l15;
#pragma unroll
  for (int r = 0; r < 4; r++) {
    zpr[r * 32] = acc0[r];
    zpr[r * 32 + 16] = acc1[r];
  }
}

// ---- passb: z_part = (Lbt @ z_k) partials; A-frags stream coalesced --------
__global__ __launch_bounds__(256) void passb_kernel(
    const u16* __restrict__ Lbt, const u16* __restrict__ zin,
    float* __restrict__ z_part) {
  const int t = threadIdx.x;
  const int lane = t & 63;
  const int w = t >> 6;
  const int l15 = lane & 15;
  const int l4 = lane >> 4;
  const int r0 = blockIdx.x * BM;
  const int s = blockIdx.y;
  const int kbase = s * CHUNK;
  const int rt = (r0 >> 4) + w;

  f32x4 acc0 = {0.f, 0.f, 0.f, 0.f};
  f32x4 acc1 = {0.f, 0.f, 0.f, 0.f};

  const u32x4* ab = (const u32x4*)(Lbt + ((size_t)rt * 256 + (kbase >> 5)) * 512) + lane;
  const u16* b0p = zin + (size_t)l15 * M_DIM + kbase + 8 * l4;
  const u16* b1p = b0p + (size_t)16 * M_DIM;

  const int KS = CHUNK / 32; // 32
#pragma unroll 4
  for (int kt = 0; kt < KS; kt++) {
    Frag fa, fb0, fb1;
    fa.q = ab[(size_t)kt * 64];               // 64 u32x4 per 1 KB tile
    fb0.q = *(const u32x4*)(b0p + kt * 32);
    fb1.q = *(const u32x4*)(b1p + kt * 32);
    acc0 = __builtin_amdgcn_mfma_f32_16x16x32_bf16(fa.f, fb0.f, acc0, 0, 0, 0);
    acc1 = __builtin_amdgcn_mfma_f32_16x16x32_bf16(fa.f, fb1.f, acc1, 0, 0, 0);
  }

  float* zpr = z_part + (size_t)s * (M_DIM * 32) +
               (size_t)(r0 + 16 * w + 4 * l4) * 32 + l15;
#pragma unroll
  for (int r = 0; r < 4; r++) {
    zpr[r * 32] = acc0[r];
    zpr[r * 32 + 16] = acc1[r];
  }
}

// ---- reduce: z = sum_s z_part[s]; y += z @ Wk; zT_out = bf16(z)^T ----------
template <bool LAST>
__global__ __launch_bounds__(256) void reduce_kernel(
    const float* __restrict__ zp, const float* __restrict__ Wk,
    const float* __restrict__ y_in, float* __restrict__ y_out,
    u16* __restrict__ zT_out) {
  __shared__ float Ws[1024];
  for (int i = threadIdx.x; i < 1024; i += 256) Ws[i] = Wk[i];
  __syncthreads();
  int m = blockIdx.x * 256 + threadIdx.x;
  float z[32];
  const float4* p0 = (const float4*)(zp + (size_t)m * 32);
#pragma unroll
  for (int i = 0; i < 8; i++) {
    float4 v = p0[i];
    z[4 * i] = v.x; z[4 * i + 1] = v.y; z[4 * i + 2] = v.z; z[4 * i + 3] = v.w;
  }
#pragma unroll
  for (int s = 1; s < S_SPLIT; s++) {
    const float4* ps = p0 + (size_t)s * (M_DIM * 32 / 4);
#pragma unroll
    for (int i = 0; i < 8; i++) {
      float4 v = ps[i];
      z[4 * i] += v.x; z[4 * i + 1] += v.y;
      z[4 * i + 2] += v.z; z[4 * i + 3] += v.w;
    }
  }
  float acc[32];
  const float4* yi = (const float4*)(y_in + (size_t)m * 32);
#pragma unroll
  for (int i = 0; i < 8; i++) {
    float4 v = yi[i];
    acc[4 * i] = v.x; acc[4 * i + 1] = v.y;
    acc[4 * i + 2] = v.z; acc[4 * i + 3] = v.w;
  }
#pragma unroll
  for (int c = 0; c < 32; c++) {
#pragma unroll
    for (int j = 0; j < 32; j++) acc[j] += z[c] * Ws[c * 32 + j];
  }
  float4* yo = (float4*)(y_out + (size_t)m * 32);
#pragma unroll
  for (int i = 0; i < 8; i++) {
    float4 v; v.x = acc[4 * i]; v.y = acc[4 * i + 1];
    v.z = acc[4 * i + 2]; v.w = acc[4 * i + 3];
    yo[i] = v;
  }
  if (!LAST) {
#pragma unroll
    for (int c = 0; c < 32; c++) zT_out[(size_t)c * M_DIM + m] = f2bf(z[c]);
  }
}

extern "C" void kernel_launch(void* const* d_in, const int* in_sizes, int n_in,
                              void* d_out, int out_size, void* d_ws,
                              size_t ws_size, hipStream_t stream) {
  const float* x = (const float*)d_in[0];
  const float* L = (const float*)d_in[1];
  const float* W = (const float*)d_in[2];
  float* y = (float*)d_out;
  char* ws = (char*)d_ws;

  const size_t ZT = (size_t)32 * M_DIM * 2; // 512 KB
  u16* zT0 = (u16*)(ws + 0 * ZT);
  u16* zT1 = (u16*)(ws + 1 * ZT);
  u16* zT2 = (u16*)(ws + 2 * ZT);
  u16* zT3 = (u16*)(ws + 3 * ZT);
  float* z_part = (float*)(ws + 4 * ZT);            // 8 MB @ 2 MiB
  float* y_acc = (float*)(ws + ((size_t)10 << 20)); // 1 MB @ 10 MiB
  u16* Lbt = (u16*)(ws + ((size_t)12 << 20));       // 128 MiB @ 12 MiB

  head_kernel<<<32, 256, 0, stream>>>(x, W, y_acc, zT0);
  pass1_kernel<<<dim3(128, S_SPLIT), 256, 0, stream>>>(L, zT0, Lbt, z_part);
  reduce_kernel<false><<<32, 256, 0, stream>>>(z_part, W + 1024, y_acc, y_acc, zT1);
  passb_kernel<<<dim3(128, S_SPLIT), 256, 0, stream>>>(Lbt, zT1, z_part);
  reduce_kernel<false><<<32, 256, 0, stream>>>(z_part, W + 2048, y_acc, y_acc, zT2);
  passb_kernel<<<dim3(128, S_SPLIT), 256, 0, stream>>>(Lbt, zT2, z_part);
  reduce_kernel<false><<<32, 256, 0, stream>>>(z_part, W + 3072, y_acc, y_acc, zT3);
  passb_kernel<<<dim3(128, S_SPLIT), 256, 0, stream>>>(Lbt, zT3, z_part);
  reduce_kernel<true><<<32, 256, 0, stream>>>(z_part, W + 4096, y_acc, y, (u16*)0);
}

// Round 3
// 199.826 us; speedup vs baseline: 2.0456x; 1.5928x over previous
//
#include <hip/hip_runtime.h>

typedef unsigned short u16;
typedef unsigned int u32;
typedef __bf16 bf16x8 __attribute__((ext_vector_type(8)));
typedef float f32x4 __attribute__((ext_vector_type(4)));
typedef u32 u32x2 __attribute__((ext_vector_type(2)));
typedef u32 u32x4 __attribute__((ext_vector_type(4)));

#define M_DIM 8192
#define S_SPLIT 8
#define CHUNK 1024           /* M_DIM / S_SPLIT */
#define CROWS 16             /* conv row tile */
#define PBM 64               /* passk row tile */

__device__ __forceinline__ u16 f2bf(float f) {
  u32 u = __builtin_bit_cast(u32, f);
  u += 0x7FFFu + ((u >> 16) & 1u);  // RNE
  return (u16)(u >> 16);
}

union Frag {
  bf16x8 f;
  u16 s[8];
  u32x2 h2[2];
  u32x4 q;
};

// zbt layout: ((kt*2 + nt)*64 + lane)*8 + j  holds z[n = nt*16+(lane&15)]
//                                            [k = kt*32 + 8*(lane>>4) + j]
// Lbt layout: ((rt*256 + ktile)*512) + lane*8 + j holds
//             L[m = rt*16+(lane&15)][k = ktile*32 + 8*(lane>>4) + j]

// ---- head: y_acc = x @ W0 ; zbt0 = frag(bf16(x)) ---------------------------
__global__ __launch_bounds__(256) void head_kernel(
    const float* __restrict__ x, const float* __restrict__ W0,
    float* __restrict__ y_out, u16* __restrict__ zbt0) {
  __shared__ float Ws[1024];
  __shared__ u16 zsb[256][34];
  const int t = threadIdx.x;
  for (int i = t; i < 1024; i += 256) Ws[i] = W0[i];
  const int m = blockIdx.x * 256 + t;
  float z[32];
  const float4* xr = (const float4*)(x + (size_t)m * 32);
#pragma unroll
  for (int i = 0; i < 8; i++) {
    float4 v = xr[i];
    z[4 * i] = v.x; z[4 * i + 1] = v.y; z[4 * i + 2] = v.z; z[4 * i + 3] = v.w;
  }
#pragma unroll
  for (int c = 0; c < 32; c++) zsb[t][c] = f2bf(z[c]);
  __syncthreads();
  float acc[32];
#pragma unroll
  for (int j = 0; j < 32; j++) acc[j] = 0.f;
#pragma unroll
  for (int c = 0; c < 32; c++) {
#pragma unroll
    for (int j = 0; j < 32; j++) acc[j] += z[c] * Ws[c * 32 + j];
  }
  float4* yo = (float4*)(y_out + (size_t)m * 32);
#pragma unroll
  for (int i = 0; i < 8; i++) {
    float4 v; v.x = acc[4 * i]; v.y = acc[4 * i + 1];
    v.z = acc[4 * i + 2]; v.w = acc[4 * i + 3];
    yo[i] = v;
  }
  // frag emit: 16 tiles (8 kt x 2 nt), 4 per wave
  const int lane = t & 63, w = t >> 6;
  const int l15 = lane & 15, l4 = lane >> 4;
#pragma unroll
  for (int i = 0; i < 4; i++) {
    int tile = w * 4 + i;
    int ktl = tile >> 1, nt = tile & 1;
    Frag fr;
#pragma unroll
    for (int j = 0; j < 8; j++) fr.s[j] = zsb[ktl * 32 + 8 * l4 + j][nt * 16 + l15];
    size_t kt_g = (size_t)blockIdx.x * 8 + ktl;
    *(u32x4*)(zbt0 + ((kt_g * 2 + nt) * 64 + lane) * 8) = fr.q;
  }
}

// ---- conv: stream L -> Lbt (frag bf16) and fuse z1 = L @ z0 partials -------
__global__ __launch_bounds__(256) void conv_kernel(
    const float* __restrict__ L, const u16* __restrict__ zbt0,
    u16* __restrict__ Lbt, float* __restrict__ z_part) {
  __shared__ u16 At[CROWS][1032];   // 33,024 B, 16B-aligned rows, pad vs banks
  __shared__ float red[4][16][33];  // 8448 B
  const int t = threadIdx.x;
  const int lane = t & 63, w = t >> 6;
  const int l15 = lane & 15, l4 = lane >> 4;
  const int bx = blockIdx.x;  // row tile [0,512)
  const int by = blockIdx.y;  // k chunk [0,8)
  const int r0 = bx * CROWS;
  const size_t kbase = (size_t)by * CHUNK;

  // stage: wave w loads rows 4w..4w+3, each row 1024 f32 = 4 x 1KB wave loads
#pragma unroll
  for (int rr = 0; rr < 4; rr++) {
    const int row = w * 4 + rr;
    const float* src = L + (size_t)(r0 + row) * M_DIM + kbase + lane * 4;
#pragma unroll
    for (int seg = 0; seg < 4; seg++) {
      float4 v = *(const float4*)(src + seg * 256);
      u32x2 p;
      p[0] = (u32)f2bf(v.x) | ((u32)f2bf(v.y) << 16);
      p[1] = (u32)f2bf(v.z) | ((u32)f2bf(v.w) << 16);
      *(u32x2*)&At[row][seg * 256 + lane * 4] = p;
    }
  }
  __syncthreads();

  // compute + Lbt emit: wave w handles chunk-local k-tiles [8w, 8w+8)
  f32x4 acc0 = {0.f, 0.f, 0.f, 0.f};
  f32x4 acc1 = {0.f, 0.f, 0.f, 0.f};
#pragma unroll
  for (int i = 0; i < 8; i++) {
    const int ktl = w * 8 + i;
    Frag fa;
    fa.q = *(const u32x4*)&At[l15][ktl * 32 + 8 * l4];
    *(u32x4*)(Lbt + ((size_t)(bx * 256 + by * 32 + ktl)) * 512 + lane * 8) = fa.q;
    Frag fb0, fb1;
    size_t bo = ((size_t)((by * 32 + ktl) * 2)) * 512 + lane * 8;
    fb0.q = *(const u32x4*)(zbt0 + bo);
    fb1.q = *(const u32x4*)(zbt0 + bo + 512);
    acc0 = __builtin_amdgcn_mfma_f32_16x16x32_bf16(fa.f, fb0.f, acc0, 0, 0, 0);
    acc1 = __builtin_amdgcn_mfma_f32_16x16x32_bf16(fa.f, fb1.f, acc1, 0, 0, 0);
  }
  // cross-wave K reduce (C layout: row = 4*l4+r, col = l15)
#pragma unroll
  for (int r = 0; r < 4; r++) {
    red[w][4 * l4 + r][l15] = acc0[r];
    red[w][4 * l4 + r][l15 + 16] = acc1[r];
  }
  __syncthreads();
  const int orow = t >> 4, ocol = t & 15;
  float v0 = red[0][orow][ocol] + red[1][orow][ocol] +
             red[2][orow][ocol] + red[3][orow][ocol];
  float v1 = red[0][orow][ocol + 16] + red[1][orow][ocol + 16] +
             red[2][orow][ocol + 16] + red[3][orow][ocol + 16];
  float* zp = z_part + (size_t)by * (M_DIM * 32) + (size_t)(r0 + orow) * 32;
  zp[ocol] = v0;
  zp[ocol + 16] = v1;
}

// ---- passk: z_part = (Lbt @ z) partials; everything contiguous -------------
__global__ __launch_bounds__(256) void passk_kernel(
    const u16* __restrict__ Lbt, const u16* __restrict__ zbt,
    float* __restrict__ z_part) {
  const int t = threadIdx.x;
  const int lane = t & 63, w = t >> 6;
  const int l15 = lane & 15, l4 = lane >> 4;
  const int bx = blockIdx.x;  // [0,128)
  const int by = blockIdx.y;  // [0,8)
  const int rt = bx * 4 + w;

  const u16* ap = Lbt + ((size_t)rt * 256 + by * 32) * 512 + lane * 8;
  const u16* bp = zbt + ((size_t)(by * 32) * 2) * 512 + lane * 8;

  f32x4 acc0 = {0.f, 0.f, 0.f, 0.f};
  f32x4 acc1 = {0.f, 0.f, 0.f, 0.f};
#pragma unroll 8
  for (int kt = 0; kt < 32; kt++) {
    Frag fa, fb0, fb1;
    fa.q = *(const u32x4*)(ap + (size_t)kt * 512);
    fb0.q = *(const u32x4*)(bp + (size_t)kt * 1024);
    fb1.q = *(const u32x4*)(bp + (size_t)kt * 1024 + 512);
    acc0 = __builtin_amdgcn_mfma_f32_16x16x32_bf16(fa.f, fb0.f, acc0, 0, 0, 0);
    acc1 = __builtin_amdgcn_mfma_f32_16x16x32_bf16(fa.f, fb1.f, acc1, 0, 0, 0);
  }
  float* zp = z_part + (size_t)by * (M_DIM * 32) +
              (size_t)(bx * PBM + w * 16 + 4 * l4) * 32 + l15;
#pragma unroll
  for (int r = 0; r < 4; r++) {
    zp[r * 32] = acc0[r];
    zp[r * 32 + 16] = acc1[r];
  }
}

// ---- reduce: z = sum_s part; y += z @ Wk; emit zbt(frag) -------------------
template <bool LAST>
__global__ __launch_bounds__(256) void reduce_kernel(
    const float* __restrict__ zp, const float* __restrict__ Wk,
    const float* __restrict__ y_in, float* __restrict__ y_out,
    u16* __restrict__ zbt_out) {
  __shared__ float Ws[1024];
  __shared__ float zs[64][33];
  __shared__ u16 zsb[64][34];
  const int t = threadIdx.x;
  for (int i = t; i < 1024; i += 256) Ws[i] = Wk[i];
  const int ml = t >> 2, cg = t & 3;
  const int m = blockIdx.x * 64 + ml;
  const float* p = zp + (size_t)m * 32 + cg * 8;
  float z8[8];
  {
    float4 lo = *(const float4*)p;
    float4 hi = *(const float4*)(p + 4);
    z8[0] = lo.x; z8[1] = lo.y; z8[2] = lo.z; z8[3] = lo.w;
    z8[4] = hi.x; z8[5] = hi.y; z8[6] = hi.z; z8[7] = hi.w;
  }
#pragma unroll
  for (int s = 1; s < S_SPLIT; s++) {
    const float* ps = p + (size_t)s * (M_DIM * 32);
    float4 lo = *(const float4*)ps;
    float4 hi = *(const float4*)(ps + 4);
    z8[0] += lo.x; z8[1] += lo.y; z8[2] += lo.z; z8[3] += lo.w;
    z8[4] += hi.x; z8[5] += hi.y; z8[6] += hi.z; z8[7] += hi.w;
  }
#pragma unroll
  for (int i = 0; i < 8; i++) {
    zs[ml][cg * 8 + i] = z8[i];
    zsb[ml][cg * 8 + i] = f2bf(z8[i]);
  }
  __syncthreads();
  float acc[8];
  {
    const float4* yi = (const float4*)(y_in + (size_t)m * 32 + cg * 8);
    float4 a0 = yi[0], a1 = yi[1];
    acc[0] = a0.x; acc[1] = a0.y; acc[2] = a0.z; acc[3] = a0.w;
    acc[4] = a1.x; acc[5] = a1.y; acc[6] = a1.z; acc[7] = a1.w;
  }
#pragma unroll
  for (int c = 0; c < 32; c++) {
    float zv = zs[ml][c];
    const float* wr = Ws + c * 32 + cg * 8;
#pragma unroll
    for (int j = 0; j < 8; j++) acc[j] += zv * wr[j];
  }
  float4* yo = (float4*)(y_out + (size_t)m * 32 + cg * 8);
  float4 o0, o1;
  o0.x = acc[0]; o0.y = acc[1]; o0.z = acc[2]; o0.w = acc[3];
  o1.x = acc[4]; o1.y = acc[5]; o1.z = acc[6]; o1.w = acc[7];
  yo[0] = o0; yo[1] = o1;

  if (!LAST) {
    // frag emit: 4 tiles (2 kt x 2 nt), one per wave
    const int lane = t & 63, w = t >> 6;
    const int l15 = lane & 15, l4 = lane >> 4;
    const int ktl = w >> 1, nt = w & 1;
    Frag fr;
#pragma unroll
    for (int j = 0; j < 8; j++)
      fr.s[j] = zsb[ktl * 32 + 8 * l4 + j][nt * 16 + l15];
    size_t kt_g = (size_t)blockIdx.x * 2 + ktl;
    *(u32x4*)(zbt_out + ((kt_g * 2 + nt) * 64 + lane) * 8) = fr.q;
  }
}

extern "C" void kernel_launch(void* const* d_in, const int* in_sizes, int n_in,
                              void* d_out, int out_size, void* d_ws,
                              size_t ws_size, hipStream_t stream) {
  const float* x = (const float*)d_in[0];
  const float* L = (const float*)d_in[1];
  const float* W = (const float*)d_in[2];
  float* y = (float*)d_out;
  char* ws = (char*)d_ws;

  const size_t ZT = (size_t)512 << 10;  // 512 KB per zbt
  u16* zbt0 = (u16*)(ws + 0 * ZT);
  u16* zbt1 = (u16*)(ws + 1 * ZT);
  u16* zbt2 = (u16*)(ws + 2 * ZT);
  u16* zbt3 = (u16*)(ws + 3 * ZT);
  float* z_part = (float*)(ws + ((size_t)2 << 20));   // 8 MB @ 2 MiB
  float* y_acc = (float*)(ws + ((size_t)10 << 20));   // 1 MB @ 10 MiB
  u16* Lbt = (u16*)(ws + ((size_t)12 << 20));         // 128 MiB @ 12 MiB

  head_kernel<<<32, 256, 0, stream>>>(x, W, y_acc, zbt0);
  conv_kernel<<<dim3(512, S_SPLIT), 256, 0, stream>>>(L, zbt0, Lbt, z_part);
  reduce_kernel<false><<<128, 256, 0, stream>>>(z_part, W + 1024, y_acc, y_acc, zbt1);
  passk_kernel<<<dim3(128, S_SPLIT), 256, 0, stream>>>(Lbt, zbt1, z_part);
  reduce_kernel<false><<<128, 256, 0, stream>>>(z_part, W + 2048, y_acc, y_acc, zbt2);
  passk_kernel<<<dim3(128, S_SPLIT), 256, 0, stream>>>(Lbt, zbt2, z_part);
  reduce_kernel<false><<<128, 256, 0, stream>>>(z_part, W + 3072, y_acc, y_acc, zbt3);
  passk_kernel<<<dim3(128, S_SPLIT), 256, 0, stream>>>(Lbt, zbt3, z_part);
  reduce_kernel<true><<<128, 256, 0, stream>>>(z_part, W + 4096, y_acc, y, (u16*)0);
}

// Round 4
// 186.537 us; speedup vs baseline: 2.1913x; 1.0712x over previous
//
#include <hip/hip_runtime.h>

typedef unsigned short u16;
typedef unsigned int u32;
typedef __bf16 bf16x8 __attribute__((ext_vector_type(8)));
typedef float f32x4 __attribute__((ext_vector_type(4)));
typedef u32 u32x2 __attribute__((ext_vector_type(2)));
typedef u32 u32x4 __attribute__((ext_vector_type(4)));

#define M_DIM 8192
#define S_SPLIT 8
#define CHUNK 1024           /* M_DIM / S_SPLIT */
#define CROWS 16             /* conv row tile */

__device__ __forceinline__ u16 f2bf(float f) {
  return __builtin_bit_cast(u16, (__bf16)f);  // HW RNE cvt (v_cvt_pk fused)
}

union Frag {
  bf16x8 f;
  u16 s[8];
  u32x2 h2[2];
  u32x4 q;
};

// zbt layout: ((kt*2 + nt)*64 + lane)*8 + j  holds z[k = kt*32 + 8*(lane>>4)+j]
//                                                  [n = nt*16 + (lane&15)]
// Lbt layout: ((rt*256 + ktile)*512) + lane*8 + j holds
//             L[m = rt*16+(lane&15)][k = ktile*32 + 8*(lane>>4) + j]

// ---- head: y_acc = x @ W0 ; zbt0 = frag(bf16(x)) ---------------------------
__global__ __launch_bounds__(256) void head_kernel(
    const float* __restrict__ x, const float* __restrict__ W0,
    float* __restrict__ y_out, u16* __restrict__ zbt0) {
  __shared__ float Ws[1024];
  __shared__ u16 zsb[256][34];
  const int t = threadIdx.x;
  for (int i = t; i < 1024; i += 256) Ws[i] = W0[i];
  const int m = blockIdx.x * 256 + t;
  float z[32];
  const float4* xr = (const float4*)(x + (size_t)m * 32);
#pragma unroll
  for (int i = 0; i < 8; i++) {
    float4 v = xr[i];
    z[4 * i] = v.x; z[4 * i + 1] = v.y; z[4 * i + 2] = v.z; z[4 * i + 3] = v.w;
  }
#pragma unroll
  for (int c = 0; c < 32; c++) zsb[t][c] = f2bf(z[c]);
  __syncthreads();
  float acc[32];
#pragma unroll
  for (int j = 0; j < 32; j++) acc[j] = 0.f;
#pragma unroll
  for (int c = 0; c < 32; c++) {
#pragma unroll
    for (int j = 0; j < 32; j++) acc[j] += z[c] * Ws[c * 32 + j];
  }
  float4* yo = (float4*)(y_out + (size_t)m * 32);
#pragma unroll
  for (int i = 0; i < 8; i++) {
    float4 v; v.x = acc[4 * i]; v.y = acc[4 * i + 1];
    v.z = acc[4 * i + 2]; v.w = acc[4 * i + 3];
    yo[i] = v;
  }
  // frag emit: 16 tiles (8 kt x 2 nt), 4 per wave
  const int lane = t & 63, w = t >> 6;
  const int l15 = lane & 15, l4 = lane >> 4;
#pragma unroll
  for (int i = 0; i < 4; i++) {
    int tile = w * 4 + i;
    int ktl = tile >> 1, nt = tile & 1;
    Frag fr;
#pragma unroll
    for (int j = 0; j < 8; j++) fr.s[j] = zsb[ktl * 32 + 8 * l4 + j][nt * 16 + l15];
    size_t kt_g = (size_t)blockIdx.x * 8 + ktl;
    *(u32x4*)(zbt0 + ((kt_g * 2 + nt) * 64 + lane) * 8) = fr.q;
  }
}

// ---- conv: stream L (nontemporal) -> Lbt (frag bf16) + fused z1 partials ---
__global__ __launch_bounds__(256) void conv_kernel(
    const float* __restrict__ L, const u16* __restrict__ zbt0,
    u16* __restrict__ Lbt, float* __restrict__ z_part) {
  __shared__ u16 At[CROWS][1032];   // padded rows
  __shared__ float red[4][16][33];
  const int t = threadIdx.x;
  const int lane = t & 63, w = t >> 6;
  const int l15 = lane & 15, l4 = lane >> 4;
  const int bx = blockIdx.x;  // row tile [0,512)
  const int by = blockIdx.y;  // k chunk [0,8)
  const int r0 = bx * CROWS;
  const size_t kbase = (size_t)by * CHUNK;

  // stage: wave w loads rows 4w..4w+3; each row-seg load = 1KB/wave contiguous
#pragma unroll
  for (int rr = 0; rr < 4; rr++) {
    const int row = w * 4 + rr;
    const float* src = L + (size_t)(r0 + row) * M_DIM + kbase + lane * 4;
#pragma unroll
    for (int seg = 0; seg < 4; seg++) {
      f32x4 v = __builtin_nontemporal_load((const f32x4*)(src + seg * 256));
      u32x2 p;
      p[0] = (u32)f2bf(v[0]) | ((u32)f2bf(v[1]) << 16);
      p[1] = (u32)f2bf(v[2]) | ((u32)f2bf(v[3]) << 16);
      *(u32x2*)&At[row][seg * 256 + lane * 4] = p;
    }
  }
  __syncthreads();

  // compute + Lbt emit: wave w handles chunk-local k-tiles [8w, 8w+8)
  f32x4 acc0 = {0.f, 0.f, 0.f, 0.f};
  f32x4 acc1 = {0.f, 0.f, 0.f, 0.f};
#pragma unroll
  for (int i = 0; i < 8; i++) {
    const int ktl = w * 8 + i;
    Frag fa;
    fa.q = *(const u32x4*)&At[l15][ktl * 32 + 8 * l4];
    *(u32x4*)(Lbt + ((size_t)(bx * 256 + by * 32 + ktl)) * 512 + lane * 8) = fa.q;
    Frag fb0, fb1;
    size_t bo = ((size_t)((by * 32 + ktl) * 2)) * 512 + lane * 8;
    fb0.q = *(const u32x4*)(zbt0 + bo);
    fb1.q = *(const u32x4*)(zbt0 + bo + 512);
    acc0 = __builtin_amdgcn_mfma_f32_16x16x32_bf16(fa.f, fb0.f, acc0, 0, 0, 0);
    acc1 = __builtin_amdgcn_mfma_f32_16x16x32_bf16(fa.f, fb1.f, acc1, 0, 0, 0);
  }
#pragma unroll
  for (int r = 0; r < 4; r++) {
    red[w][4 * l4 + r][l15] = acc0[r];
    red[w][4 * l4 + r][l15 + 16] = acc1[r];
  }
  __syncthreads();
  const int orow = t >> 4, ocol = t & 15;
  float v0 = red[0][orow][ocol] + red[1][orow][ocol] +
             red[2][orow][ocol] + red[3][orow][ocol];
  float v1 = red[0][orow][ocol + 16] + red[1][orow][ocol + 16] +
             red[2][orow][ocol + 16] + red[3][orow][ocol + 16];
  float* zp = z_part + (size_t)by * (M_DIM * 32) + (size_t)(r0 + orow) * 32;
  zp[ocol] = v0;
  zp[ocol + 16] = v1;
}

// ---- reduce (after conv only): z1 = sum parts; y += z1@W1; emit zbt1 -------
__global__ __launch_bounds__(256) void reduce_kernel(
    const float* __restrict__ zp, const float* __restrict__ Wk,
    const float* __restrict__ y_in, float* __restrict__ y_out,
    u16* __restrict__ zbt_out) {
  __shared__ float Ws[1024];
  __shared__ float zs[64][33];
  __shared__ u16 zsb[64][34];
  const int t = threadIdx.x;
  for (int i = t; i < 1024; i += 256) Ws[i] = Wk[i];
  const int ml = t >> 2, cg = t & 3;
  const int m = blockIdx.x * 64 + ml;
  const float* p = zp + (size_t)m * 32 + cg * 8;
  float z8[8];
  {
    float4 lo = *(const float4*)p;
    float4 hi = *(const float4*)(p + 4);
    z8[0] = lo.x; z8[1] = lo.y; z8[2] = lo.z; z8[3] = lo.w;
    z8[4] = hi.x; z8[5] = hi.y; z8[6] = hi.z; z8[7] = hi.w;
  }
#pragma unroll
  for (int s = 1; s < S_SPLIT; s++) {
    const float* ps = p + (size_t)s * (M_DIM * 32);
    float4 lo = *(const float4*)ps;
    float4 hi = *(const float4*)(ps + 4);
    z8[0] += lo.x; z8[1] += lo.y; z8[2] += lo.z; z8[3] += lo.w;
    z8[4] += hi.x; z8[5] += hi.y; z8[6] += hi.z; z8[7] += hi.w;
  }
#pragma unroll
  for (int i = 0; i < 8; i++) {
    zs[ml][cg * 8 + i] = z8[i];
    zsb[ml][cg * 8 + i] = f2bf(z8[i]);
  }
  __syncthreads();
  float acc[8];
  {
    const float4* yi = (const float4*)(y_in + (size_t)m * 32 + cg * 8);
    float4 a0 = yi[0], a1 = yi[1];
    acc[0] = a0.x; acc[1] = a0.y; acc[2] = a0.z; acc[3] = a0.w;
    acc[4] = a1.x; acc[5] = a1.y; acc[6] = a1.z; acc[7] = a1.w;
  }
#pragma unroll
  for (int c = 0; c < 32; c++) {
    float zv = zs[ml][c];
    const float* wr = Ws + c * 32 + cg * 8;
#pragma unroll
    for (int j = 0; j < 8; j++) acc[j] += zv * wr[j];
  }
  float4* yo = (float4*)(y_out + (size_t)m * 32 + cg * 8);
  float4 o0, o1;
  o0.x = acc[0]; o0.y = acc[1]; o0.z = acc[2]; o0.w = acc[3];
  o1.x = acc[4]; o1.y = acc[5]; o1.z = acc[6]; o1.w = acc[7];
  yo[0] = o0; yo[1] = o1;

  // frag emit: 4 tiles (2 kt x 2 nt), one per wave
  const int lane = t & 63, w = t >> 6;
  const int l15 = lane & 15, l4 = lane >> 4;
  const int ktl = w >> 1, nt = w & 1;
  Frag fr;
#pragma unroll
  for (int j = 0; j < 8; j++)
    fr.s[j] = zsb[ktl * 32 + 8 * l4 + j][nt * 16 + l15];
  size_t kt_g = (size_t)blockIdx.x * 2 + ktl;
  *(u32x4*)(zbt_out + ((kt_g * 2 + nt) * 64 + lane) * 8) = fr.q;
}

// ---- fpass: full-K pass fused with reduce + y+=z@Wk + zbt emit -------------
// Block: 16 output rows, 8 waves K-split 1024 each, LDS 8-way reduce.
template <bool LAST>
__global__ __launch_bounds__(512, 4) void fpass_kernel(
    const u16* __restrict__ Lbt, const u16* __restrict__ zbt,
    const float* __restrict__ Wk, const float* __restrict__ y_in,
    float* __restrict__ y_out, u16* __restrict__ zbt_out) {
  __shared__ float red[8][16][33];
  __shared__ float Ws[1024];
  __shared__ float zs[16][33];
  __shared__ u16 zsb[16][36];
  const int t = threadIdx.x;
  const int lane = t & 63, w = t >> 6;
  const int l15 = lane & 15, l4 = lane >> 4;
  const int bx = blockIdx.x;  // [0,512) row tile
  for (int i = t; i < 1024; i += 512) Ws[i] = Wk[i];

  const u16* ap = Lbt + ((size_t)bx * 256 + w * 32) * 512 + lane * 8;
  const u16* bp = zbt + (size_t)(w * 32) * 1024 + lane * 8;

  f32x4 acc0 = {0.f, 0.f, 0.f, 0.f};
  f32x4 acc1 = {0.f, 0.f, 0.f, 0.f};
#pragma unroll 8
  for (int kt = 0; kt < 32; kt++) {
    Frag fa, fb0, fb1;
    fa.q = *(const u32x4*)(ap + (size_t)kt * 512);
    fb0.q = *(const u32x4*)(bp + (size_t)kt * 1024);
    fb1.q = *(const u32x4*)(bp + (size_t)kt * 1024 + 512);
    acc0 = __builtin_amdgcn_mfma_f32_16x16x32_bf16(fa.f, fb0.f, acc0, 0, 0, 0);
    acc1 = __builtin_amdgcn_mfma_f32_16x16x32_bf16(fa.f, fb1.f, acc1, 0, 0, 0);
  }
#pragma unroll
  for (int r = 0; r < 4; r++) {
    red[w][4 * l4 + r][l15] = acc0[r];
    red[w][4 * l4 + r][l15 + 16] = acc1[r];
  }
  __syncthreads();
  const int row = t >> 5, j = t & 31;  // 16 rows x 32 cols
  float v = 0.f;
#pragma unroll
  for (int s = 0; s < 8; s++) v += red[s][row][j];
  zs[row][j] = v;
  zsb[row][j] = f2bf(v);
  __syncthreads();
  float yv = y_in[(size_t)(bx * 16 + row) * 32 + j];
#pragma unroll
  for (int c = 0; c < 32; c++) yv += zs[row][c] * Ws[c * 32 + j];
  y_out[(size_t)(bx * 16 + row) * 32 + j] = yv;

  if (!LAST && t < 64) {
    const int nt = t >> 5, li = t & 31;
    const int kt = bx >> 1, h = bx & 1;
    Frag fr;
#pragma unroll
    for (int jj = 0; jj < 8; jj++)
      fr.s[jj] = zsb[8 * (li >> 4) + jj][nt * 16 + (li & 15)];
    *(u32x4*)(zbt_out + (size_t)((kt * 2 + nt) * 64 + 32 * h + li) * 8) = fr.q;
  }
}

extern "C" void kernel_launch(void* const* d_in, const int* in_sizes, int n_in,
                              void* d_out, int out_size, void* d_ws,
                              size_t ws_size, hipStream_t stream) {
  const float* x = (const float*)d_in[0];
  const float* L = (const float*)d_in[1];
  const float* W = (const float*)d_in[2];
  float* y = (float*)d_out;
  char* ws = (char*)d_ws;

  const size_t ZT = (size_t)512 << 10;  // 512 KB per zbt
  u16* zbt0 = (u16*)(ws + 0 * ZT);
  u16* zbt1 = (u16*)(ws + 1 * ZT);
  u16* zbt2 = (u16*)(ws + 2 * ZT);
  u16* zbt3 = (u16*)(ws + 3 * ZT);
  float* z_part = (float*)(ws + ((size_t)2 << 20));   // 8 MB @ 2 MiB
  float* y_acc = (float*)(ws + ((size_t)10 << 20));   // 1 MB @ 10 MiB
  u16* Lbt = (u16*)(ws + ((size_t)12 << 20));         // 128 MiB @ 12 MiB

  head_kernel<<<32, 256, 0, stream>>>(x, W, y_acc, zbt0);
  conv_kernel<<<dim3(512, S_SPLIT), 256, 0, stream>>>(L, zbt0, Lbt, z_part);
  reduce_kernel<<<128, 256, 0, stream>>>(z_part, W + 1024, y_acc, y_acc, zbt1);
  fpass_kernel<false><<<512, 512, 0, stream>>>(Lbt, zbt1, W + 2048, y_acc, y_acc, zbt2);
  fpass_kernel<false><<<512, 512, 0, stream>>>(Lbt, zbt2, W + 3072, y_acc, y_acc, zbt3);
  fpass_kernel<true><<<512, 512, 0, stream>>>(Lbt, zbt3, W + 4096, y_acc, y, (u16*)0);
}

// Round 5
// 174.535 us; speedup vs baseline: 2.3420x; 1.0688x over previous
//
#include <hip/hip_runtime.h>

typedef unsigned short u16;
typedef unsigned int u32;
typedef __bf16 bf16x8 __attribute__((ext_vector_type(8)));
typedef float f32x4 __attribute__((ext_vector_type(4)));
typedef u32 u32x2 __attribute__((ext_vector_type(2)));
typedef u32 u32x4 __attribute__((ext_vector_type(4)));

#define M_DIM 8192
#define CCH 512              /* conv staging chunk (k-cols) */
#define NCH (M_DIM / CCH)    /* 16 chunks */

__device__ __forceinline__ u16 f2bf(float f) {
  return __builtin_bit_cast(u16, (__bf16)f);  // HW RNE cvt
}

union Frag {
  bf16x8 f;
  u16 s[8];
  u32x2 h2[2];
  u32x4 q;
};

// zbt layout: ((kt*2 + nt)*64 + lane)*8 + j holds z[k = kt*32 + 8*(lane>>4)+j]
//                                                 [n = nt*16 + (lane&15)]
// Lbt layout: ((rt*256 + ktile)*512) + lane*8 + j holds
//             L[m = rt*16+(lane&15)][k = ktile*32 + 8*(lane>>4) + j]

// ---- head: y_acc = x @ W0 ; zbt0 = frag(bf16(x)) ---------------------------
__global__ __launch_bounds__(256) void head_kernel(
    const float* __restrict__ x, const float* __restrict__ W0,
    float* __restrict__ y_out, u16* __restrict__ zbt0) {
  __shared__ float Ws[1024];
  __shared__ u16 zsb[256][34];
  const int t = threadIdx.x;
  for (int i = t; i < 1024; i += 256) Ws[i] = W0[i];
  const int m = blockIdx.x * 256 + t;
  float z[32];
  const float4* xr = (const float4*)(x + (size_t)m * 32);
#pragma unroll
  for (int i = 0; i < 8; i++) {
    float4 v = xr[i];
    z[4 * i] = v.x; z[4 * i + 1] = v.y; z[4 * i + 2] = v.z; z[4 * i + 3] = v.w;
  }
#pragma unroll
  for (int c = 0; c < 32; c++) zsb[t][c] = f2bf(z[c]);
  __syncthreads();
  float acc[32];
#pragma unroll
  for (int j = 0; j < 32; j++) acc[j] = 0.f;
#pragma unroll
  for (int c = 0; c < 32; c++) {
#pragma unroll
    for (int j = 0; j < 32; j++) acc[j] += z[c] * Ws[c * 32 + j];
  }
  float4* yo = (float4*)(y_out + (size_t)m * 32);
#pragma unroll
  for (int i = 0; i < 8; i++) {
    float4 v; v.x = acc[4 * i]; v.y = acc[4 * i + 1];
    v.z = acc[4 * i + 2]; v.w = acc[4 * i + 3];
    yo[i] = v;
  }
  const int lane = t & 63, w = t >> 6;
  const int l15 = lane & 15, l4 = lane >> 4;
#pragma unroll
  for (int i = 0; i < 4; i++) {
    int tile = w * 4 + i;
    int ktl = tile >> 1, nt = tile & 1;
    Frag fr;
#pragma unroll
    for (int j = 0; j < 8; j++) fr.s[j] = zsb[ktl * 32 + 8 * l4 + j][nt * 16 + l15];
    size_t kt_g = (size_t)blockIdx.x * 8 + ktl;
    *(u32x4*)(zbt0 + ((kt_g * 2 + nt) * 64 + lane) * 8) = fr.q;
  }
}

// ---- conv: full-K fused. stream L -> Lbt + z1 = L@z0 + y+=z1@W1 + emit zbt1.
// Block: 16 rows, 8 waves, dbuf 512-col chunks, 8-way LDS K-reduce.
__global__ __launch_bounds__(512, 4) void conv_kernel(
    const float* __restrict__ L, const u16* __restrict__ zbt0,
    const float* __restrict__ W1, const float* __restrict__ y_in,
    float* __restrict__ y_out, u16* __restrict__ Lbt,
    u16* __restrict__ zbt_out) {
  __shared__ u16 At[2][16][520];    // 33.3 KB, pad 8 u16 -> ~2-way banks
  __shared__ float red[8][16][33];  // 16.9 KB
  __shared__ float Ws[1024];
  __shared__ float zs[16][33];
  __shared__ u16 zsb[16][36];
  const int t = threadIdx.x;
  const int lane = t & 63, w = t >> 6;
  const int l15 = lane & 15, l4 = lane >> 4;
  const int bx = blockIdx.x;  // [0,512) row tile
  const int r0 = bx * 16;
  for (int i = t; i < 1024; i += 512) Ws[i] = W1[i];

  const int srow = t >> 5, scg = t & 31;
  const float* sbase = L + (size_t)(r0 + srow) * M_DIM + scg * 4;

  auto stage = [&](int c, int buf) {
    const float* src = sbase + c * CCH;
    u16* dst = &At[buf][srow][scg * 4];
#pragma unroll
    for (int seg = 0; seg < 4; seg++) {
      f32x4 v = __builtin_nontemporal_load((const f32x4*)(src + seg * 128));
      u32x2 p;
      p[0] = (u32)f2bf(v[0]) | ((u32)f2bf(v[1]) << 16);
      p[1] = (u32)f2bf(v[2]) | ((u32)f2bf(v[3]) << 16);
      *(u32x2*)(dst + seg * 128) = p;
    }
  };

  f32x4 acc0 = {0.f, 0.f, 0.f, 0.f};
  f32x4 acc1 = {0.f, 0.f, 0.f, 0.f};

  stage(0, 0);
  int buf = 0;
  for (int c = 0; c < NCH; c++) {
    __syncthreads();
    if (c + 1 < NCH) stage(c + 1, buf ^ 1);
#pragma unroll
    for (int i = 0; i < 2; i++) {
      const int ktl = c * 16 + w * 2 + i;  // global k-tile [0,256)
      Frag fa;
      fa.q = *(const u32x4*)&At[buf][l15][(w * 2 + i) * 32 + 8 * l4];
      *(u32x4*)(Lbt + ((size_t)bx * 256 + ktl) * 512 + lane * 8) = fa.q;
      Frag fb0, fb1;
      size_t bo = ((size_t)ktl * 2) * 512 + lane * 8;
      fb0.q = *(const u32x4*)(zbt0 + bo);
      fb1.q = *(const u32x4*)(zbt0 + bo + 512);
      acc0 = __builtin_amdgcn_mfma_f32_16x16x32_bf16(fa.f, fb0.f, acc0, 0, 0, 0);
      acc1 = __builtin_amdgcn_mfma_f32_16x16x32_bf16(fa.f, fb1.f, acc1, 0, 0, 0);
    }
    buf ^= 1;
  }

#pragma unroll
  for (int r = 0; r < 4; r++) {
    red[w][4 * l4 + r][l15] = acc0[r];
    red[w][4 * l4 + r][l15 + 16] = acc1[r];
  }
  __syncthreads();
  const int row = t >> 5, j = t & 31;
  float v = 0.f;
#pragma unroll
  for (int s = 0; s < 8; s++) v += red[s][row][j];
  zs[row][j] = v;
  zsb[row][j] = f2bf(v);
  __syncthreads();
  float yv = y_in[(size_t)(r0 + row) * 32 + j];
#pragma unroll
  for (int c = 0; c < 32; c++) yv += zs[row][c] * Ws[c * 32 + j];
  y_out[(size_t)(r0 + row) * 32 + j] = yv;

  if (t < 64) {
    const int nt = t >> 5, li = t & 31;
    const int kt = bx >> 1, h = bx & 1;
    Frag fr;
#pragma unroll
    for (int jj = 0; jj < 8; jj++)
      fr.s[jj] = zsb[8 * (li >> 4) + jj][nt * 16 + (li & 15)];
    *(u32x4*)(zbt_out + (size_t)((kt * 2 + nt) * 64 + 32 * h + li) * 8) = fr.q;
  }
}

// ---- fpass: full-K pass fused with reduce + y+=z@Wk + zbt emit -------------
template <bool LAST>
__global__ __launch_bounds__(512, 4) void fpass_kernel(
    const u16* __restrict__ Lbt, const u16* __restrict__ zbt,
    const float* __restrict__ Wk, const float* __restrict__ y_in,
    float* __restrict__ y_out, u16* __restrict__ zbt_out) {
  __shared__ float red[8][16][33];
  __shared__ float Ws[1024];
  __shared__ float zs[16][33];
  __shared__ u16 zsb[16][36];
  const int t = threadIdx.x;
  const int lane = t & 63, w = t >> 6;
  const int l15 = lane & 15, l4 = lane >> 4;
  const int bx = blockIdx.x;  // [0,512) row tile
  for (int i = t; i < 1024; i += 512) Ws[i] = Wk[i];

  const u16* ap = Lbt + ((size_t)bx * 256 + w * 32) * 512 + lane * 8;
  const u16* bp = zbt + (size_t)(w * 32) * 1024 + lane * 8;

  f32x4 acc0 = {0.f, 0.f, 0.f, 0.f};
  f32x4 acc1 = {0.f, 0.f, 0.f, 0.f};
#pragma unroll 8
  for (int kt = 0; kt < 32; kt++) {
    Frag fa, fb0, fb1;
    fa.q = *(const u32x4*)(ap + (size_t)kt * 512);
    fb0.q = *(const u32x4*)(bp + (size_t)kt * 1024);
    fb1.q = *(const u32x4*)(bp + (size_t)kt * 1024 + 512);
    acc0 = __builtin_amdgcn_mfma_f32_16x16x32_bf16(fa.f, fb0.f, acc0, 0, 0, 0);
    acc1 = __builtin_amdgcn_mfma_f32_16x16x32_bf16(fa.f, fb1.f, acc1, 0, 0, 0);
  }
#pragma unroll
  for (int r = 0; r < 4; r++) {
    red[w][4 * l4 + r][l15] = acc0[r];
    red[w][4 * l4 + r][l15 + 16] = acc1[r];
  }
  __syncthreads();
  const int row = t >> 5, j = t & 31;
  float v = 0.f;
#pragma unroll
  for (int s = 0; s < 8; s++) v += red[s][row][j];
  zs[row][j] = v;
  zsb[row][j] = f2bf(v);
  __syncthreads();
  float yv = y_in[(size_t)(bx * 16 + row) * 32 + j];
#pragma unroll
  for (int c = 0; c < 32; c++) yv += zs[row][c] * Ws[c * 32 + j];
  y_out[(size_t)(bx * 16 + row) * 32 + j] = yv;

  if (!LAST && t < 64) {
    const int nt = t >> 5, li = t & 31;
    const int kt = bx >> 1, h = bx & 1;
    Frag fr;
#pragma unroll
    for (int jj = 0; jj < 8; jj++)
      fr.s[jj] = zsb[8 * (li >> 4) + jj][nt * 16 + (li & 15)];
    *(u32x4*)(zbt_out + (size_t)((kt * 2 + nt) * 64 + 32 * h + li) * 8) = fr.q;
  }
}

extern "C" void kernel_launch(void* const* d_in, const int* in_sizes, int n_in,
                              void* d_out, int out_size, void* d_ws,
                              size_t ws_size, hipStream_t stream) {
  const float* x = (const float*)d_in[0];
  const float* L = (const float*)d_in[1];
  const float* W = (const float*)d_in[2];
  float* y = (float*)d_out;
  char* ws = (char*)d_ws;

  const size_t ZT = (size_t)512 << 10;  // 512 KB per zbt
  u16* zbt0 = (u16*)(ws + 0 * ZT);
  u16* zbt1 = (u16*)(ws + 1 * ZT);
  u16* zbt2 = (u16*)(ws + 2 * ZT);
  u16* zbt3 = (u16*)(ws + 3 * ZT);
  float* y_acc = (float*)(ws + ((size_t)10 << 20));   // 1 MB @ 10 MiB
  u16* Lbt = (u16*)(ws + ((size_t)12 << 20));         // 128 MiB @ 12 MiB

  head_kernel<<<32, 256, 0, stream>>>(x, W, y_acc, zbt0);
  conv_kernel<<<512, 512, 0, stream>>>(L, zbt0, W + 1024, y_acc, y_acc, Lbt, zbt1);
  fpass_kernel<false><<<512, 512, 0, stream>>>(Lbt, zbt1, W + 2048, y_acc, y_acc, zbt2);
  fpass_kernel<false><<<512, 512, 0, stream>>>(Lbt, zbt2, W + 3072, y_acc, y_acc, zbt3);
  fpass_kernel<true><<<512, 512, 0, stream>>>(Lbt, zbt3, W + 4096, y_acc, y, (u16*)0);
}